// Round 4
// baseline (213.072 us; speedup 1.0000x reference)
//
#include <hip/hip_runtime.h>
#include <hip/hip_bf16.h>

typedef __bf16 bf16x8 __attribute__((ext_vector_type(8)));
typedef float f32x4 __attribute__((ext_vector_type(4)));
typedef float f32x16 __attribute__((ext_vector_type(16)));

#define SEQ   2048
#define NHEAD 12
#define NBH   24
#define QSCALE 0.18033688011112042f   // head_dim^-0.5 * log2(e)

// async global->LDS 16B copy; lds dest must be wave-uniform base + lane*16
#define CP16(g, l) __builtin_amdgcn_global_load_lds( \
    (const __attribute__((address_space(1))) unsigned int*)(g), \
    (__attribute__((address_space(3))) unsigned int*)(l), 16, 0, 0)

__device__ __forceinline__ unsigned short f2bf(float f) {
  unsigned int u = __builtin_bit_cast(unsigned int, f);
  u += 0x7FFFu + ((u >> 16) & 1u);
  return (unsigned short)(u >> 16);
}
__device__ __forceinline__ float bfu2f(unsigned int lo16_as_hi) {
  return __builtin_bit_cast(float, lo16_as_hi);
}
// truncating pack of two f32 -> bf16x2 in one v_perm_b32 (P in [0,1]; dominant weight is
// exactly 1.0 under running-max so top terms carry zero pack error — PROVEN at 1.95e-3).
__device__ __forceinline__ unsigned int packbf2_trunc(float lo, float hi) {
  return __builtin_amdgcn_perm(__builtin_bit_cast(unsigned int, hi),
                               __builtin_bit_cast(unsigned int, lo), 0x07060302u);
}
// exact tree max of 16 (compiler fuses to v_max3); depth 4 vs serial depth 16
__device__ __forceinline__ float vmax16(const f32x16& s) {
  float a = fmaxf(fmaxf(s[0], s[1]), fmaxf(s[2], s[3]));
  float b = fmaxf(fmaxf(s[4], s[5]), fmaxf(s[6], s[7]));
  float c = fmaxf(fmaxf(s[8], s[9]), fmaxf(s[10], s[11]));
  float d = fmaxf(fmaxf(s[12], s[13]), fmaxf(s[14], s[15]));
  return fmaxf(fmaxf(a, b), fmaxf(c, d));
}

// ---------------------------------------------------------------- fused cvt fp32->bf16
#define NX4  786432
#define NW14 442368
__global__ __launch_bounds__(256) void cvt3_kernel(const float4* __restrict__ x,
                                                   const float4* __restrict__ w1,
                                                   const float4* __restrict__ w2,
                                                   ushort4* __restrict__ xo,
                                                   ushort4* __restrict__ w1o,
                                                   ushort4* __restrict__ w2o) {
  int i = blockIdx.x * 256 + threadIdx.x;
  const float4* s;
  ushort4* d;
  int j = i;
  if (i < NX4)               { s = x;  d = xo; }
  else if (i < NX4 + NW14)   { s = w1; d = w1o; j = i - NX4; }
  else                       { s = w2; d = w2o; j = i - (NX4 + NW14); }
  float4 v = s[j];
  ushort4 r;
  r.x = f2bf(v.x); r.y = f2bf(v.y); r.z = f2bf(v.z); r.w = f2bf(v.w);
  d[j] = r;
}

// ---------------------------------------------------------------- GEMM  C = X @ W^T (+bias)
// async staging: LDS slot e holds global chunk (c8 ^ (r&7)) of row r -> reads use XOR swizzle.
template <int BM, int BN, int MODE>
__global__ __launch_bounds__(256) void gemm_kernel(const unsigned short* __restrict__ X,
                                                   const unsigned short* __restrict__ W,
                                                   const float* __restrict__ bias,
                                                   unsigned short* __restrict__ Qb,
                                                   unsigned short* __restrict__ Kb,
                                                   unsigned short* __restrict__ Vtb,
                                                   float* __restrict__ Out) {
  constexpr int K = 768, BK = 64;
  constexpr int WM = BM / 2, WN = BN / 2;
  constexpr int MT = WM / 16, NT = WN / 16;
  __shared__ __align__(16) unsigned short Xs[BM * BK];
  __shared__ __align__(16) unsigned short Ws[BN * BK];

  const int tid = threadIdx.x;
  const int w = tid >> 6, lane = tid & 63, quad = lane >> 4, m16 = lane & 15;
  const int wm = w & 1, wn = w >> 1;
  const int row0 = blockIdx.y * BM, col0 = blockIdx.x * BN;

  f32x4 acc[MT][NT];
#pragma unroll
  for (int mt = 0; mt < MT; ++mt)
#pragma unroll
    for (int nt = 0; nt < NT; ++nt) acc[mt][nt] = (f32x4){0.f, 0.f, 0.f, 0.f};

  for (int k0 = 0; k0 < K; k0 += BK) {
    __syncthreads();
#pragma unroll
    for (int j = 0; j < BM / 32; ++j) {
      int e = tid + 256 * j, r = e >> 3, c8 = e & 7;
      CP16(X + (size_t)(row0 + r) * 768 + k0 + ((c8 ^ (r & 7)) << 3), Xs + e * 8);
    }
#pragma unroll
    for (int j = 0; j < BN / 32; ++j) {
      int e = tid + 256 * j, r = e >> 3, c8 = e & 7;
      CP16(W + (size_t)(col0 + r) * 768 + k0 + ((c8 ^ (r & 7)) << 3), Ws + e * 8);
    }
    __syncthreads();
#pragma unroll
    for (int ks = 0; ks < 2; ++ks) {
      const int sw = ((quad + 4 * ks) ^ (m16 & 7)) << 3;
      bf16x8 a[MT], b[NT];
#pragma unroll
      for (int mt = 0; mt < MT; ++mt)
        a[mt] = *(const bf16x8*)(Xs + (wm * WM + mt * 16 + m16) * BK + sw);
#pragma unroll
      for (int nt = 0; nt < NT; ++nt)
        b[nt] = *(const bf16x8*)(Ws + (wn * WN + nt * 16 + m16) * BK + sw);
#pragma unroll
      for (int mt = 0; mt < MT; ++mt)
#pragma unroll
        for (int nt = 0; nt < NT; ++nt)
          acc[mt][nt] = __builtin_amdgcn_mfma_f32_16x16x32_bf16(a[mt], b[nt], acc[mt][nt], 0, 0, 0);
    }
  }

#pragma unroll
  for (int mt = 0; mt < MT; ++mt) {
#pragma unroll
    for (int nt = 0; nt < NT; ++nt) {
      const int m0 = row0 + wm * WM + mt * 16 + quad * 4;
      const int c = col0 + wn * WN + nt * 16 + m16;
      const float bia = bias[c];
      f32x4 v = acc[mt][nt];
      if constexpr (MODE == 0) {
        const int bidx = m0 >> 11, ns = m0 & 2047;
        if (c < 1536) {   // Q or K: [bh][n][d]
          unsigned short* dst;
          float sc;
          int cc;
          if (c < 768) { cc = c; dst = Qb; sc = QSCALE; }
          else         { cc = c - 768; dst = Kb; sc = 1.0f; }
          const int h = cc >> 6, d = cc & 63;
          unsigned short* p = dst + ((size_t)(bidx * NHEAD + h) * SEQ + ns) * 64 + d;
          p[0]   = f2bf((v[0] + bia) * sc);
          p[64]  = f2bf((v[1] + bia) * sc);
          p[128] = f2bf((v[2] + bia) * sc);
          p[192] = f2bf((v[3] + bia) * sc);
        } else {          // V transposed [bh][d][n], sigma-permuted keys (bits2<->3 of n&15)
          const int cc = c - 1536, h = cc >> 6, d = cc & 63;
          const int ns2 = (ns & ~12) | ((ns & 4) << 1) | ((ns & 8) >> 1);
          ushort4 pk;
          pk.x = f2bf(v[0] + bia); pk.y = f2bf(v[1] + bia);
          pk.z = f2bf(v[2] + bia); pk.w = f2bf(v[3] + bia);
          *(ushort4*)(Vtb + ((size_t)(bidx * NHEAD + h) * 64 + d) * SEQ + ns2) = pk;
        }
      } else {
        float* o = Out + (size_t)m0 * 768 + c;
        o[0]       = v[0] + bia;
        o[768]     = v[1] + bia;
        o[2 * 768] = v[2] + bia;
        o[3 * 768] = v[3] + bia;
      }
    }
  }
}

// ---------------------------------------------------------------- flash attention (no-LDS)
// Round-4 restructure based on falsified rounds 0/3 theories: kernel was latency-bound
// (1.5 waves/SIMD) with the LDS pipe ~50-60% busy (both waves read IDENTICAL K/V fragments
// from LDS; 3.1M conflict cycles). K/V are L2-resident per-XCD, so LDS staging was a
// redundant L2 copy. This version:
//  - loads K/V MFMA fragments DIRECTLY from global (the staging XOR-swizzle and the read
//    un-swizzle provably cancel: kf = K[t0+t32*32+l32][dc*16+hi*8+..] — register contents
//    are bit-identical to the proven round-0 path)
//  - no LDS, no CP16, no barriers: 1-wave blocks, fully independent
//  - 2-way KEY SPLIT for occupancy: 3072 blocks (12 waves/CU vs 6) each doing 16 key-tiles,
//    writing unnormalized O (bf16 RNE) + (m,l) f32 partials into dead ws regions; a combine
//    kernel merges. Per-half running max keeps dominant weight exactly 1.0 (round-1 lesson).
__global__ __launch_bounds__(64) void attn_kernel(const unsigned short* __restrict__ Qb,
                                                  const unsigned short* __restrict__ Kb,
                                                  const unsigned short* __restrict__ Vtb,
                                                  unsigned short* __restrict__ O0,
                                                  unsigned short* __restrict__ O1,
                                                  float2* __restrict__ ml) {
  const int lane = threadIdx.x, hi = lane >> 5, l32 = lane & 31;
  const int bh = blockIdx.x % NBH;            // same bh -> same XCD (24%8==0, 3072%24==0)
  const int rest = blockIdx.x / NBH;          // [0,128)
  const int qt = rest & 63, half = rest >> 6;
  const int bb = bh / NHEAD, h = bh % NHEAD;
  const int q0 = qt * 32;

  // Q B-frags: lane holds Q[q0+l32][dc*16 + hi*8 + j]
  const unsigned short* Qp = Qb + (size_t)bh * SEQ * 64;
  bf16x8 qf[4];
#pragma unroll
  for (int dc = 0; dc < 4; ++dc)
    qf[dc] = *(const bf16x8*)(Qp + (size_t)(q0 + l32) * 64 + dc * 16 + hi * 8);

  // per-lane global fragment bases; k advances 8KB/tile, v advances 128B/tile
  const int kt0 = half * 16;
  const unsigned short* k0p = Kb + (size_t)bh * SEQ * 64 + (size_t)(kt0 * 64 + l32) * 64 + hi * 8;
  const unsigned short* k1p = k0p + 32 * 64;
  const unsigned short* v0p = Vtb + (size_t)bh * 64 * SEQ + (size_t)l32 * SEQ + kt0 * 64 + hi * 8;
  const unsigned short* v1p = v0p + (size_t)32 * SEQ;

  f32x16 o[2] = {};
  float m_i = -3.0e38f, l_i = 0.f;

#pragma unroll 2
  for (int kt = 0; kt < 16; ++kt) {
    // issue all 16 fragment loads (compiler inserts fine-grained vmcnt before first use)
    bf16x8 kf[2][4], vf[2][4];
#pragma unroll
    for (int c = 0; c < 4; ++c) {
      kf[0][c] = *(const bf16x8*)(k0p + c * 16);
      kf[1][c] = *(const bf16x8*)(k1p + c * 16);
      vf[0][c] = *(const bf16x8*)(v0p + c * 16);
      vf[1][c] = *(const bf16x8*)(v1p + c * 16);
    }
    k0p += 4096; k1p += 4096; v0p += 64; v1p += 64;

    // S^T: st[t32] holds S^T[key = t32*32 + (r&3)+8*(r>>2)+4*hi][q = l32]
    __builtin_amdgcn_s_setprio(1);
    f32x16 st[2];
#pragma unroll
    for (int t32 = 0; t32 < 2; ++t32) {
      f32x16 s = {};
#pragma unroll
      for (int dc = 0; dc < 4; ++dc)
        s = __builtin_amdgcn_mfma_f32_32x32x16_bf16(kf[t32][dc], qf[dc], s, 0, 0, 0);
      st[t32] = s;
    }
    __builtin_amdgcn_s_setprio(0);

    // online softmax (proven math): lane holds 32 scores; partner (^32) has the other 32
    float tmax = fmaxf(vmax16(st[0]), vmax16(st[1]));
    tmax = fmaxf(tmax, __shfl_xor(tmax, 32));
    const float mnew = fmaxf(m_i, tmax);
    const float alpha = __builtin_amdgcn_exp2f(m_i - mnew);
    m_i = mnew;
    l_i *= alpha;
    o[0] *= alpha;
    o[1] *= alpha;

    float ts[2];
#pragma unroll
    for (int t32 = 0; t32 < 2; ++t32) {
      float pv[16];
#pragma unroll
      for (int e = 0; e < 16; ++e) pv[e] = __builtin_amdgcn_exp2f(st[t32][e] - mnew);
      unsigned int pf[8];
#pragma unroll
      for (int e2 = 0; e2 < 8; ++e2)
        pf[e2] = packbf2_trunc(pv[2 * e2], pv[2 * e2 + 1]);
      const float a = (pv[0] + pv[1]) + (pv[2] + pv[3]);
      const float b = (pv[4] + pv[5]) + (pv[6] + pv[7]);
      const float c = (pv[8] + pv[9]) + (pv[10] + pv[11]);
      const float d = (pv[12] + pv[13]) + (pv[14] + pv[15]);
      ts[t32] = (a + b) + (c + d);
      // O^T += Vt . P^T  (fused per t32; vf column pair cc = 2*t32+hh)
      __builtin_amdgcn_s_setprio(1);
#pragma unroll
      for (int hh = 0; hh < 2; ++hh) {
        bf16x8 pfrag = __builtin_bit_cast(bf16x8,
            make_uint4(pf[hh * 4], pf[hh * 4 + 1], pf[hh * 4 + 2], pf[hh * 4 + 3]));
        const int cc = 2 * t32 + hh;
#pragma unroll
        for (int dt = 0; dt < 2; ++dt)
          o[dt] = __builtin_amdgcn_mfma_f32_32x32x16_bf16(vf[dt][cc], pfrag, o[dt], 0, 0, 0);
      }
      __builtin_amdgcn_s_setprio(0);
    }
    float ssum = ts[0] + ts[1];
    ssum += __shfl_xor(ssum, 32);
    l_i += ssum;
  }

  // epilogue: write UNNORMALIZED O partial (bf16 RNE) + (m,l); combine kernel normalizes.
  // lane's q = q0 + l32; o element d = dt*32 + 8*(r>>2) + 4*hi + (r&3)
  unsigned short* base = (half ? O1 : O0) + ((size_t)bb * SEQ + q0 + l32) * 768 + h * 64;
#pragma unroll
  for (int dt = 0; dt < 2; ++dt) {
#pragma unroll
    for (int run = 0; run < 4; ++run) {
      ushort4 pk;
      pk.x = f2bf(o[dt][run * 4 + 0]);
      pk.y = f2bf(o[dt][run * 4 + 1]);
      pk.z = f2bf(o[dt][run * 4 + 2]);
      pk.w = f2bf(o[dt][run * 4 + 3]);
      *(ushort4*)(base + dt * 32 + run * 8 + hi * 4) = pk;
    }
  }
  if (hi == 0)
    ml[(size_t)half * (NBH * SEQ) + bh * SEQ + q0 + l32] = make_float2(m_i, l_i);
}

// ---------------------------------------------------------------- combine partial halves
// O = (a0*O0 + a1*O1) / (a0*l0 + a1*l1), a_i = exp2(m_i - max(m0,m1)). In-place into O0.
// 196608 threads: one 16-elem chunk of the [4096][768] buffer each.
__global__ __launch_bounds__(256) void combine_kernel(unsigned short* __restrict__ O0,
                                                      const unsigned short* __restrict__ O1,
                                                      const float2* __restrict__ ml) {
  const int gid = blockIdx.x * 256 + threadIdx.x;   // [0, 196608)
  const int t = gid / 48, ci = gid - t * 48;        // token, 16-ch chunk
  const int ch0 = ci * 16, h = ch0 >> 6;
  const int mlrow = ((t >> 11) * NHEAD + h) * SEQ + (t & 2047);
  const float2 ml0 = ml[mlrow], ml1 = ml[NBH * SEQ + mlrow];
  const float m = fmaxf(ml0.x, ml1.x);
  const float a0 = __builtin_amdgcn_exp2f(ml0.x - m);
  const float a1 = __builtin_amdgcn_exp2f(ml1.x - m);
  const float rl = __builtin_amdgcn_rcpf(a0 * ml0.y + a1 * ml1.y);
  const float s0 = a0 * rl, s1 = a1 * rl;
  unsigned short* p0 = O0 + (size_t)t * 768 + ch0;
  const unsigned short* p1 = O1 + (size_t)t * 768 + ch0;
  uint4 x[2], y[2];
  x[0] = *(const uint4*)p0;       x[1] = *(const uint4*)(p0 + 8);
  y[0] = *(const uint4*)p1;       y[1] = *(const uint4*)(p1 + 8);
#pragma unroll
  for (int q = 0; q < 2; ++q) {
    unsigned int* xu = (unsigned int*)&x[q];
    const unsigned int* yu = (const unsigned int*)&y[q];
#pragma unroll
    for (int e = 0; e < 4; ++e) {
      const unsigned int u0 = xu[e], u1 = yu[e];
      const float lo = bfu2f(u0 << 16) * s0 + bfu2f(u1 << 16) * s1;
      const float hi = bfu2f(u0 & 0xFFFF0000u) * s0 + bfu2f(u1 & 0xFFFF0000u) * s1;
      xu[e] = ((unsigned int)f2bf(hi) << 16) | f2bf(lo);
    }
  }
  *(uint4*)p0 = x[0];
  *(uint4*)(p0 + 8) = x[1];
}

// ---------------------------------------------------------------- launch
extern "C" void kernel_launch(void* const* d_in, const int* in_sizes, int n_in,
                              void* d_out, int out_size, void* d_ws, size_t ws_size,
                              hipStream_t stream) {
  const float* x      = (const float*)d_in[0];
  const float* qkv_w  = (const float*)d_in[1];
  const float* qkv_b  = (const float*)d_in[2];
  const float* proj_w = (const float*)d_in[3];
  const float* proj_b = (const float*)d_in[4];
  float* out = (float*)d_out;

  unsigned short* xb  = (unsigned short*)d_ws;     // dead after gemm1 -> reused as O1 partial
  unsigned short* wqb = xb + 3145728;              // dead after gemm1 -> reused as ml partials
  unsigned short* wpb = wqb + 1769472;
  unsigned short* Qb  = wpb + 589824;
  unsigned short* Kb  = Qb + 3145728;
  unsigned short* Vtb = Kb + 3145728;
  unsigned short* Ab  = Vtb + 3145728;             // O0 partial, combined in-place

  cvt3_kernel<<<5376, 256, 0, stream>>>((const float4*)x, (const float4*)qkv_w, (const float4*)proj_w,
                                        (ushort4*)xb, (ushort4*)wqb, (ushort4*)wpb);
  gemm_kernel<128, 96, 0><<<dim3(24, 32), 256, 0, stream>>>(xb, wqb, qkv_b, Qb, Kb, Vtb, nullptr);
  attn_kernel<<<3072, 64, 0, stream>>>(Qb, Kb, Vtb, Ab, xb, (float2*)wqb);
  combine_kernel<<<768, 256, 0, stream>>>(Ab, xb, (const float2*)wqb);
  gemm_kernel<64, 96, 1><<<dim3(8, 64), 256, 0, stream>>>(Ab, wpb, proj_b, nullptr, nullptr, nullptr, out);
}

// Round 5
// 186.345 us; speedup vs baseline: 1.1434x; 1.1434x over previous
//
#include <hip/hip_runtime.h>
#include <hip/hip_bf16.h>

typedef __bf16 bf16x8 __attribute__((ext_vector_type(8)));
typedef float f32x4 __attribute__((ext_vector_type(4)));
typedef float f32x16 __attribute__((ext_vector_type(16)));

#define SEQ   2048
#define NHEAD 12
#define NBH   24
#define QSCALE 0.18033688011112042f   // head_dim^-0.5 * log2(e)

// async global->LDS 16B copy; lds dest must be wave-uniform base + lane*16
#define CP16(g, l) __builtin_amdgcn_global_load_lds( \
    (const __attribute__((address_space(1))) unsigned int*)(g), \
    (__attribute__((address_space(3))) unsigned int*)(l), 16, 0, 0)

__device__ __forceinline__ unsigned short f2bf(float f) {
  unsigned int u = __builtin_bit_cast(unsigned int, f);
  u += 0x7FFFu + ((u >> 16) & 1u);
  return (unsigned short)(u >> 16);
}
// truncating pack of two f32 -> bf16x2 in one v_perm_b32 (P in [0,1]; dominant weight is
// exactly 1.0 under running-max so top terms carry zero pack error — PROVEN at 1.95e-3).
__device__ __forceinline__ unsigned int packbf2_trunc(float lo, float hi) {
  return __builtin_amdgcn_perm(__builtin_bit_cast(unsigned int, hi),
                               __builtin_bit_cast(unsigned int, lo), 0x07060302u);
}
// exact tree max of 16 (compiler fuses to v_max3); depth 4 vs serial depth 16
__device__ __forceinline__ float vmax16(const f32x16& s) {
  float a = fmaxf(fmaxf(s[0], s[1]), fmaxf(s[2], s[3]));
  float b = fmaxf(fmaxf(s[4], s[5]), fmaxf(s[6], s[7]));
  float c = fmaxf(fmaxf(s[8], s[9]), fmaxf(s[10], s[11]));
  float d = fmaxf(fmaxf(s[12], s[13]), fmaxf(s[14], s[15]));
  return fmaxf(fmaxf(a, b), fmaxf(c, d));
}

// ---------------------------------------------------------------- fused cvt fp32->bf16
#define NX4  786432
#define NW14 442368
__global__ __launch_bounds__(256) void cvt3_kernel(const float4* __restrict__ x,
                                                   const float4* __restrict__ w1,
                                                   const float4* __restrict__ w2,
                                                   ushort4* __restrict__ xo,
                                                   ushort4* __restrict__ w1o,
                                                   ushort4* __restrict__ w2o) {
  int i = blockIdx.x * 256 + threadIdx.x;
  const float4* s;
  ushort4* d;
  int j = i;
  if (i < NX4)               { s = x;  d = xo; }
  else if (i < NX4 + NW14)   { s = w1; d = w1o; j = i - NX4; }
  else                       { s = w2; d = w2o; j = i - (NX4 + NW14); }
  float4 v = s[j];
  ushort4 r;
  r.x = f2bf(v.x); r.y = f2bf(v.y); r.z = f2bf(v.z); r.w = f2bf(v.w);
  d[j] = r;
}

// ---------------------------------------------------------------- GEMM  C = X @ W^T (+bias)
// async staging: LDS slot e holds global chunk (c8 ^ (r&7)) of row r -> reads use XOR swizzle.
template <int BM, int BN, int MODE>
__global__ __launch_bounds__(256) void gemm_kernel(const unsigned short* __restrict__ X,
                                                   const unsigned short* __restrict__ W,
                                                   const float* __restrict__ bias,
                                                   unsigned short* __restrict__ Qb,
                                                   unsigned short* __restrict__ Kb,
                                                   unsigned short* __restrict__ Vtb,
                                                   float* __restrict__ Out) {
  constexpr int K = 768, BK = 64;
  constexpr int WM = BM / 2, WN = BN / 2;
  constexpr int MT = WM / 16, NT = WN / 16;
  __shared__ __align__(16) unsigned short Xs[BM * BK];
  __shared__ __align__(16) unsigned short Ws[BN * BK];

  const int tid = threadIdx.x;
  const int w = tid >> 6, lane = tid & 63, quad = lane >> 4, m16 = lane & 15;
  const int wm = w & 1, wn = w >> 1;
  const int row0 = blockIdx.y * BM, col0 = blockIdx.x * BN;

  f32x4 acc[MT][NT];
#pragma unroll
  for (int mt = 0; mt < MT; ++mt)
#pragma unroll
    for (int nt = 0; nt < NT; ++nt) acc[mt][nt] = (f32x4){0.f, 0.f, 0.f, 0.f};

  for (int k0 = 0; k0 < K; k0 += BK) {
    __syncthreads();
#pragma unroll
    for (int j = 0; j < BM / 32; ++j) {
      int e = tid + 256 * j, r = e >> 3, c8 = e & 7;
      CP16(X + (size_t)(row0 + r) * 768 + k0 + ((c8 ^ (r & 7)) << 3), Xs + e * 8);
    }
#pragma unroll
    for (int j = 0; j < BN / 32; ++j) {
      int e = tid + 256 * j, r = e >> 3, c8 = e & 7;
      CP16(W + (size_t)(col0 + r) * 768 + k0 + ((c8 ^ (r & 7)) << 3), Ws + e * 8);
    }
    __syncthreads();
#pragma unroll
    for (int ks = 0; ks < 2; ++ks) {
      const int sw = ((quad + 4 * ks) ^ (m16 & 7)) << 3;
      bf16x8 a[MT], b[NT];
#pragma unroll
      for (int mt = 0; mt < MT; ++mt)
        a[mt] = *(const bf16x8*)(Xs + (wm * WM + mt * 16 + m16) * BK + sw);
#pragma unroll
      for (int nt = 0; nt < NT; ++nt)
        b[nt] = *(const bf16x8*)(Ws + (wn * WN + nt * 16 + m16) * BK + sw);
#pragma unroll
      for (int mt = 0; mt < MT; ++mt)
#pragma unroll
        for (int nt = 0; nt < NT; ++nt)
          acc[mt][nt] = __builtin_amdgcn_mfma_f32_16x16x32_bf16(a[mt], b[nt], acc[mt][nt], 0, 0, 0);
    }
  }

#pragma unroll
  for (int mt = 0; mt < MT; ++mt) {
#pragma unroll
    for (int nt = 0; nt < NT; ++nt) {
      const int m0 = row0 + wm * WM + mt * 16 + quad * 4;
      const int c = col0 + wn * WN + nt * 16 + m16;
      const float bia = bias[c];
      f32x4 v = acc[mt][nt];
      if constexpr (MODE == 0) {
        const int bidx = m0 >> 11, ns = m0 & 2047;
        if (c < 1536) {   // Q or K: [bh][n][d]
          unsigned short* dst;
          float sc;
          int cc;
          if (c < 768) { cc = c; dst = Qb; sc = QSCALE; }
          else         { cc = c - 768; dst = Kb; sc = 1.0f; }
          const int h = cc >> 6, d = cc & 63;
          unsigned short* p = dst + ((size_t)(bidx * NHEAD + h) * SEQ + ns) * 64 + d;
          p[0]   = f2bf((v[0] + bia) * sc);
          p[64]  = f2bf((v[1] + bia) * sc);
          p[128] = f2bf((v[2] + bia) * sc);
          p[192] = f2bf((v[3] + bia) * sc);
        } else {          // V transposed [bh][d][n], sigma-permuted keys (bits2<->3 of n&15)
          const int cc = c - 1536, h = cc >> 6, d = cc & 63;
          const int ns2 = (ns & ~12) | ((ns & 4) << 1) | ((ns & 8) >> 1);
          ushort4 pk;
          pk.x = f2bf(v[0] + bia); pk.y = f2bf(v[1] + bia);
          pk.z = f2bf(v[2] + bia); pk.w = f2bf(v[3] + bia);
          *(ushort4*)(Vtb + ((size_t)(bidx * NHEAD + h) * 64 + d) * SEQ + ns2) = pk;
        }
      } else {
        float* o = Out + (size_t)m0 * 768 + c;
        o[0]       = v[0] + bia;
        o[768]     = v[1] + bia;
        o[2 * 768] = v[2] + bia;
        o[3 * 768] = v[3] + bia;
      }
    }
  }
}

// ---------------------------------------------------------------- flash attention
// 768 blocks = 24 bh x 32 q-tiles(64); 2 waves x 32 q (round-3 structure: LDS staging is the
// coalescing transformer — round 4 proved direct-global frag loads are a 32-line scatter).
//
// Round-5 change: REGISTER-LEVEL K-FRAG PREFETCH. K frags for tile kt+1 are ds_read during
// iter kt, so QK^T starts immediately at the barrier (ds latency off the critical path).
// Requires K 4-buffered in LDS (period-4 static indexing via 4x-unrolled body); V stays
// double-buffered (its reads are consumed only after softmax — natural slack).
// Hazards: CP16 K(kt+2)->kbuf[(kt+2)%4] (last read 3 barriers ago); V(kt+1) vs vf(kt) use
// opposite parities; tiles 32/33 stage garbage from adjacent ws buffers (valid, unused).
// l_i -> per-lane lacc partials (removes per-iter ssum shfl; exact up to reassociation).
// LDS: K 4x8KB @ 0..16383 shorts, V 2x8KB @ 16384..24575 shorts = 48KB total.
__global__ __launch_bounds__(128, 1) void attn_kernel(const unsigned short* __restrict__ Qb,
                                                      const unsigned short* __restrict__ Kb,
                                                      const unsigned short* __restrict__ Vtb,
                                                      unsigned short* __restrict__ Ab) {
  __shared__ __align__(16) unsigned short S[24576];

  const int tid = threadIdx.x;
  const int w = tid >> 6, lane = tid & 63, hi = lane >> 5, l32 = lane & 31;
  const int bh = blockIdx.x % NBH, qt = blockIdx.x / NBH;   // same bh -> same XCD (24%8==0)
  const int bb = bh / NHEAD, h = bh % NHEAD;
  const int q0 = qt * 64 + w * 32;

  const unsigned short* Qp = Qb + (size_t)bh * SEQ * 64;
  const unsigned short* Kp = Kb + (size_t)bh * SEQ * 64;
  const unsigned short* Vp = Vtb + (size_t)bh * 64 * SEQ;

  // Q B-frags: lane holds Q[q0+l32][dc*16 + hi*8 + j]
  bf16x8 qf[4];
#pragma unroll
  for (int dc = 0; dc < 4; ++dc)
    qf[dc] = *(const bf16x8*)(Qp + (size_t)(q0 + l32) * 64 + dc * 16 + hi * 8);

  // hoisted per-lane LDS read pointers (kbuf0 / vbuf0); other buffers via +const offsets
  const unsigned short* dsK[2][4];
  const unsigned short* dsV[2][4];
#pragma unroll
  for (int t32 = 0; t32 < 2; ++t32)
#pragma unroll
    for (int c = 0; c < 4; ++c) {
      dsK[t32][c] = &S[(t32 * 32 + l32) * 64 + ((((c << 1) | hi) ^ (l32 & 7)) << 3)];
      dsV[t32][c] = dsK[t32][c] + 16384;
    }

  // hoisted per-lane staging source pointers + LDS dest base
  const unsigned short* Kst[4];
  const unsigned short* Vst[4];
#pragma unroll
  for (int j = 0; j < 4; ++j) {
    const int e = tid + 128 * j, r = e >> 3, sw = ((e & 7) ^ (r & 7)) << 3;
    Kst[j] = Kp + r * 64 + sw;
    Vst[j] = Vp + r * SEQ + sw;
  }
  const int edst = tid * 8;

  // prologue: stage K(0)->kbuf0, V(0)->vbuf0; sync; read kf(0); stage K(1)->kbuf1
#pragma unroll
  for (int j = 0; j < 4; ++j) {
    CP16(Kst[j], &S[edst + 1024 * j]);
    CP16(Vst[j], &S[16384 + edst + 1024 * j]);
  }
  __syncthreads();
  bf16x8 kfA[2][4], kfB[2][4];
#pragma unroll
  for (int t32 = 0; t32 < 2; ++t32)
#pragma unroll
    for (int c = 0; c < 4; ++c)
      kfA[t32][c] = *(const bf16x8*)(dsK[t32][c]);
#pragma unroll
  for (int j = 0; j < 4; ++j)
    CP16(Kst[j] + 4096, &S[4096 + edst + 1024 * j]);

  f32x16 o[2] = {};
  f32x16 lacc = {};
  float m_i = -3.0e38f;

  // one tile step: J = kt&3 (static); KC = current frags (tile kt), KN = next (tile kt+1)
#define TILE_STEP(J, KC, KN)                                                              \
  {                                                                                       \
    __syncthreads(); /* drains CP16 K(kt+1),V(kt) + prior ds_reads */                     \
    _Pragma("unroll") for (int t32 = 0; t32 < 2; ++t32)                                   \
      _Pragma("unroll") for (int c = 0; c < 4; ++c)                                       \
        KN[t32][c] = *(const bf16x8*)(dsK[t32][c] + (((J) + 1) & 3) * 4096);              \
    bf16x8 vf[2][4];                                                                      \
    _Pragma("unroll") for (int dt = 0; dt < 2; ++dt)                                      \
      _Pragma("unroll") for (int c = 0; c < 4; ++c)                                       \
        vf[dt][c] = *(const bf16x8*)(dsV[dt][c] + ((J) & 1) * 4096);                      \
    _Pragma("unroll") for (int jj = 0; jj < 4; ++jj) {                                    \
      CP16(Kst[jj] + kt4 * 16384 + ((J) + 2) * 4096,                                      \
           &S[(((J) + 2) & 3) * 4096 + edst + 1024 * jj]);                                \
      CP16(Vst[jj] + kt4 * 256 + ((J) + 1) * 64,                                          \
           &S[16384 + (((J) + 1) & 1) * 4096 + edst + 1024 * jj]);                        \
    }                                                                                     \
    __builtin_amdgcn_s_setprio(1);                                                        \
    f32x16 st[2];                                                                         \
    _Pragma("unroll") for (int t32 = 0; t32 < 2; ++t32) {                                 \
      f32x16 s = {};                                                                      \
      _Pragma("unroll") for (int dc = 0; dc < 4; ++dc)                                    \
        s = __builtin_amdgcn_mfma_f32_32x32x16_bf16(KC[t32][dc], qf[dc], s, 0, 0, 0);     \
      st[t32] = s;                                                                        \
    }                                                                                     \
    __builtin_amdgcn_s_setprio(0);                                                        \
    float tmax = fmaxf(vmax16(st[0]), vmax16(st[1]));                                     \
    tmax = fmaxf(tmax, __shfl_xor(tmax, 32));                                             \
    const float mnew = fmaxf(m_i, tmax);                                                  \
    const float alpha = __builtin_amdgcn_exp2f(m_i - mnew);                               \
    m_i = mnew;                                                                           \
    o[0] *= alpha;                                                                        \
    o[1] *= alpha;                                                                        \
    lacc *= alpha;                                                                        \
    unsigned int pf[2][8];                                                                \
    _Pragma("unroll") for (int t32 = 0; t32 < 2; ++t32) {                                 \
      float pv[16];                                                                       \
      _Pragma("unroll") for (int e = 0; e < 16; ++e)                                      \
        pv[e] = __builtin_amdgcn_exp2f(st[t32][e] - mnew);                                \
      _Pragma("unroll") for (int e = 0; e < 16; ++e) lacc[e] += pv[e];                    \
      _Pragma("unroll") for (int e2 = 0; e2 < 8; ++e2)                                    \
        pf[t32][e2] = packbf2_trunc(pv[2 * e2], pv[2 * e2 + 1]);                          \
    }                                                                                     \
    __builtin_amdgcn_s_setprio(1);                                                        \
    _Pragma("unroll") for (int t32 = 0; t32 < 2; ++t32)                                   \
      _Pragma("unroll") for (int hh = 0; hh < 2; ++hh) {                                  \
        bf16x8 pfrag = __builtin_bit_cast(bf16x8,                                         \
            make_uint4(pf[t32][hh * 4], pf[t32][hh * 4 + 1],                              \
                       pf[t32][hh * 4 + 2], pf[t32][hh * 4 + 3]));                        \
        _Pragma("unroll") for (int dt = 0; dt < 2; ++dt)                                  \
          o[dt] = __builtin_amdgcn_mfma_f32_32x32x16_bf16(vf[dt][2 * t32 + hh], pfrag,    \
                                                          o[dt], 0, 0, 0);                \
      }                                                                                   \
    __builtin_amdgcn_s_setprio(0);                                                        \
  }

  for (int kt4 = 0; kt4 < 8; ++kt4) {
    TILE_STEP(0, kfA, kfB)
    TILE_STEP(1, kfB, kfA)
    TILE_STEP(2, kfA, kfB)
    TILE_STEP(3, kfB, kfA)
  }
#undef TILE_STEP

  // epilogue: fold l partials; lane pair (l, l^32) holds the two key-halves of q = q0+l32
  float l4[4];
#pragma unroll
  for (int g = 0; g < 4; ++g)
    l4[g] = (lacc[4 * g] + lacc[4 * g + 1]) + (lacc[4 * g + 2] + lacc[4 * g + 3]);
  float lsum = (l4[0] + l4[1]) + (l4[2] + l4[3]);
  lsum += __shfl_xor(lsum, 32);
  const float rl = __builtin_amdgcn_rcpf(lsum);

  // lane's q = q0 + l32; o element d = dt*32 + 8*(r>>2) + 4*hi + (r&3)
  unsigned short* base = Ab + ((size_t)bb * SEQ + q0 + l32) * 768 + h * 64;
#pragma unroll
  for (int dt = 0; dt < 2; ++dt) {
#pragma unroll
    for (int run = 0; run < 4; ++run) {
      ushort4 pk;
      pk.x = f2bf(o[dt][run * 4 + 0] * rl);
      pk.y = f2bf(o[dt][run * 4 + 1] * rl);
      pk.z = f2bf(o[dt][run * 4 + 2] * rl);
      pk.w = f2bf(o[dt][run * 4 + 3] * rl);
      *(ushort4*)(base + dt * 32 + run * 8 + hi * 4) = pk;
    }
  }
}

// ---------------------------------------------------------------- launch
extern "C" void kernel_launch(void* const* d_in, const int* in_sizes, int n_in,
                              void* d_out, int out_size, void* d_ws, size_t ws_size,
                              hipStream_t stream) {
  const float* x      = (const float*)d_in[0];
  const float* qkv_w  = (const float*)d_in[1];
  const float* qkv_b  = (const float*)d_in[2];
  const float* proj_w = (const float*)d_in[3];
  const float* proj_b = (const float*)d_in[4];
  float* out = (float*)d_out;

  unsigned short* xb  = (unsigned short*)d_ws;
  unsigned short* wqb = xb + 3145728;
  unsigned short* wpb = wqb + 1769472;
  unsigned short* Qb  = wpb + 589824;
  unsigned short* Kb  = Qb + 3145728;
  unsigned short* Vtb = Kb + 3145728;
  unsigned short* Ab  = Vtb + 3145728;

  cvt3_kernel<<<5376, 256, 0, stream>>>((const float4*)x, (const float4*)qkv_w, (const float4*)proj_w,
                                        (ushort4*)xb, (ushort4*)wqb, (ushort4*)wpb);
  gemm_kernel<128, 96, 0><<<dim3(24, 32), 256, 0, stream>>>(xb, wqb, qkv_b, Qb, Kb, Vtb, nullptr);
  attn_kernel<<<768, 128, 0, stream>>>(Qb, Kb, Vtb, Ab);
  gemm_kernel<64, 96, 1><<<dim3(8, 64), 256, 0, stream>>>(Ab, wpb, proj_b, nullptr, nullptr, nullptr, out);
}